// Round 1
// baseline (1792.493 us; speedup 1.0000x reference)
//
#include <hip/hip_runtime.h>
#include <math.h>

// SDE Euler-Maruyama, triangular schedule.
// Design: 2 particles per wave (32 lanes each). Lane lam (0..31) owns hidden
// units j0=lam, j1=lam+32. y is DISTRIBUTED: lane holds y[dstar] where
// dstar = bitrev3(lam&7) (4 replicas across lam&7 groups). Layer-1 uses a
// 7-shfl xor-rotation with rotation-permuted W1 registers; layer-2 partials
// are reduced with a select-fold (3 stages) + xor8/xor16, which lands the
// sum for dimension dstar exactly on the lanes that own y[dstar].
// Noise is prefetched 4 steps deep (one row per unrolled sub-step).

#define NPART 4096
#define ROWSTRIDE 32768   // N*D floats per noise row
#define LASTROW 4094      // valid noise rows: 0..4094

__device__ __forceinline__ float fast_tanh(float x) {
#if __has_builtin(__builtin_amdgcn_exp2f) && __has_builtin(__builtin_amdgcn_rcpf)
  float e = __builtin_amdgcn_exp2f(x * 2.8853900817779268f);   // e^{2x}
  return __builtin_fmaf(-2.0f, __builtin_amdgcn_rcpf(e + 1.0f), 1.0f);
#else
  float e = __expf(2.0f * x);
  return 1.0f - 2.0f / (e + 1.0f);
#endif
}

__global__ __launch_bounds__(256, 2) void sde_kernel(
    const float* __restrict__ z0, const int* __restrict__ idx,
    const float* __restrict__ W1, const float* __restrict__ b1,
    const float* __restrict__ W2, const float* __restrict__ b2,
    const float* __restrict__ log_noise, const float* __restrict__ noise,
    float* __restrict__ out)
{
  const int tid   = threadIdx.x;
  const int lane  = tid & 63;
  const int wv    = tid >> 6;        // wave in block 0..3
  const int lam   = lane & 31;       // lane within particle group
  const int pslot = lane >> 5;       // 0/1
  const int base  = blockIdx.x * 8 + wv * 2;
  const int P     = base + pslot;    // this lane's particle
  const int pmax  = base + 1;        // steps to run (chain length of P1)
  const int j0 = lam, j1 = lam + 32;

  const int lb = lam & 7;
  const int dstar = ((lb & 1) << 2) | (lb & 2) | ((lb >> 2) & 1);  // bitrev3

  // ---- weights in registers ----
  float w1a[8], w1b[8], w2a[8], w2b[8];
#pragma unroll
  for (int r = 0; r < 8; ++r) {
    int xr = (lam ^ r) & 7;
    int dd = ((xr & 1) << 2) | (xr & 2) | ((xr >> 2) & 1);   // dim of lane lam^r
    w1a[r] = W1[dd * 64 + j0];
    w1b[r] = W1[dd * 64 + j1];
  }
  const float bb1a = b1[j0], bb1b = b1[j1];
#pragma unroll
  for (int d = 0; d < 8; ++d) {
    w2a[d] = W2[j0 * 8 + d];
    w2b[d] = W2[j1 * 8 + d];
  }
  const float b2loc = b2[dstar];

  const float dt   = 1.0f / 4095.0f;
  const float csig = __expf(log_noise[0]) * sqrtf(dt);

  float y = z0[(size_t)idx[P] * 8 + dstar];

  // particle 0 records its initial state (0 steps)
  if (P == 0 && lam < 8) out[dstar] = y;

  // ---- noise prefetch: rows 0..3 feed steps 1..4 ----
  const float* np = noise + ((size_t)P * 8 + dstar);
  float e0 = np[0];
  float e1 = np[(size_t)1 * ROWSTRIDE];
  float e2 = np[(size_t)2 * ROWSTRIDE];
  float e3 = np[(size_t)3 * ROWSTRIDE];
  np += (size_t)4 * ROWSTRIDE;
  int nld = 4;  // next row index to load

  auto step = [&](float ee, int sstep) {
    // layer 1: pre_j = b1[j] + sum_d y_d * W1[d][j]  (xor-rotation over 8 lanes)
    float pa = __builtin_fmaf(y, w1a[0], bb1a);
    float pb = __builtin_fmaf(y, w1b[0], bb1b);
#pragma unroll
    for (int r = 1; r < 8; ++r) {
      float yr = __shfl_xor(y, r, 64);
      pa = __builtin_fmaf(yr, w1a[r], pa);
      pb = __builtin_fmaf(yr, w1b[r], pb);
    }
    float ha = fast_tanh(pa);
    float hb = fast_tanh(pb);
    // layer 2 partials (canonical d order)
    float acc[8];
#pragma unroll
    for (int d = 0; d < 8; ++d)
      acc[d] = __builtin_fmaf(hb, w2b[d], ha * w2a[d]);
    // select-fold 8 values over 8 lanes -> 1 value (dim dstar) per lane
    {
      float t;
      const bool s0 = (lam & 1);
      t = s0 ? acc[0] : acc[4]; t = __shfl_xor(t, 1, 64); acc[0] = (s0 ? acc[4] : acc[0]) + t;
      t = s0 ? acc[1] : acc[5]; t = __shfl_xor(t, 1, 64); acc[1] = (s0 ? acc[5] : acc[1]) + t;
      t = s0 ? acc[2] : acc[6]; t = __shfl_xor(t, 1, 64); acc[2] = (s0 ? acc[6] : acc[2]) + t;
      t = s0 ? acc[3] : acc[7]; t = __shfl_xor(t, 1, 64); acc[3] = (s0 ? acc[7] : acc[3]) + t;
      const bool s1 = (lam & 2);
      t = s1 ? acc[0] : acc[2]; t = __shfl_xor(t, 2, 64); acc[0] = (s1 ? acc[2] : acc[0]) + t;
      t = s1 ? acc[1] : acc[3]; t = __shfl_xor(t, 2, 64); acc[1] = (s1 ? acc[3] : acc[1]) + t;
      const bool s2 = (lam & 4);
      t = s2 ? acc[0] : acc[1]; t = __shfl_xor(t, 4, 64); acc[0] = (s2 ? acc[1] : acc[0]) + t;
    }
    float a0 = acc[0];
    a0 += __shfl_xor(a0, 8, 64);
    a0 += __shfl_xor(a0, 16, 64);
    float drift = a0 + b2loc;
    // Euler-Maruyama update
    y = __builtin_fmaf(drift, dt, __builtin_fmaf(csig, ee, y));
    // record particle P after step sstep == P
    if (sstep == P && lam < 8) out[(size_t)P * 8 + dstar] = y;
  };

  for (int s = 1; s <= pmax; s += 4) {
    step(e0, s);
    if (nld <= LASTROW) { e0 = *np; } np += ROWSTRIDE; ++nld;
    step(e1, s + 1);
    if (nld <= LASTROW) { e1 = *np; } np += ROWSTRIDE; ++nld;
    step(e2, s + 2);
    if (nld <= LASTROW) { e2 = *np; } np += ROWSTRIDE; ++nld;
    step(e3, s + 3);
    if (nld <= LASTROW) { e3 = *np; } np += ROWSTRIDE; ++nld;
  }
}

extern "C" void kernel_launch(void* const* d_in, const int* in_sizes, int n_in,
                              void* d_out, int out_size, void* d_ws, size_t ws_size,
                              hipStream_t stream) {
  const float* z0    = (const float*)d_in[0];
  const int*   idx   = (const int*)d_in[1];
  const float* W1    = (const float*)d_in[2];
  const float* b1    = (const float*)d_in[3];
  const float* W2    = (const float*)d_in[4];
  const float* b2    = (const float*)d_in[5];
  const float* ln    = (const float*)d_in[6];
  const float* noise = (const float*)d_in[7];
  float* out = (float*)d_out;
  // 512 blocks x 256 threads = 2048 waves; wave w owns particles {2w, 2w+1}
  hipLaunchKernelGGL(sde_kernel, dim3(512), dim3(256), 0, stream,
                     z0, idx, W1, b1, W2, b2, ln, noise, out);
}

// Round 3
// 983.196 us; speedup vs baseline: 1.8231x; 1.8231x over previous
//
#include <hip/hip_runtime.h>
#include <math.h>

// SDE Euler-Maruyama, triangular schedule, ALL cross-lane ops VALU-only.
//
// Layout per wave (64 lanes): 2 particles. Lane bits:
//   bits 0,1 = q      : dim-slot, lane owns dims {2q, 2q+1} of y
//   bits 2,3,5        : replica index (8 replicas of the quad)
//   bit 4   = pslot   : which of the wave's 2 particles
// 32 lanes per particle hold 64 hidden units (2 per lane, j0=lam32, j1=lam32+32).
//
// Cross-lane moves used (all VALU, no DS):
//   quad_perm xor1/2/3 (DPP), row_half_mirror (xor7), row_mirror (xor15),
//   v_permlane32_swap_b32 (xor32). xor4 = RHM∘quad3, xor8 = RM∘RHM.
// Local dim order d = 2q ^ i makes the quad fold select-free.
//
// HAZARD FIX (round 3): v_permlane32_swap_b32 is issued from raw inline asm,
// so the compiler does NOT insert the required wait states between the
// preceding VALU write of its source VGPRs and the permlane read (it does
// for builtins). s_nop 1 before + s_nop 1 after provide the wait states.
//
// SIMD balancing: block B wave v<4 -> pair k=4B+v (short chain), wave v+4 ->
// k=2047-4B-v (long chain). Waves v and v+4 share a SIMD (v%4 round-robin),
// so every SIMD totals exactly 4096 wave-steps.

#define ROW2 16384          // float2 elements per noise row (4096*8/2)
#define LASTROW 4094        // valid noise rows 0..4094

template<int CTRL>
__device__ __forceinline__ float fdpp(float x) {
  return __builtin_bit_cast(float, __builtin_amdgcn_update_dpp(
      0, __builtin_bit_cast(int, x), CTRL, 0xF, 0xF, true));
}

// value from lane^4:  RHM gives x[l^7], quad xor3 of that gives x[l^4]
__device__ __forceinline__ float get_x4(float x) {
  return fdpp<0x1B>(fdpp<0x141>(x));
}
// value from lane^8:  RM gives x[l^15], RHM of that gives x[l^8]
__device__ __forceinline__ float get_x8(float x) {
  return fdpp<0x141>(fdpp<0x140>(x));
}
// x + x[lane^32] via v_permlane32_swap (gfx950, VALU).
// s_nop 1 on both sides = manual wait states (inline asm gets no compiler
// hazard mitigation).
__device__ __forceinline__ float sum_x32(float x) {
  float a = x, b = x;
  asm("s_nop 1\n\t"
      "v_permlane32_swap_b32 %0, %1\n\t"
      "s_nop 1"
      : "+v"(a), "+v"(b));
  return a + b;
}

__device__ __forceinline__ float fast_tanh(float x) {
#if __has_builtin(__builtin_amdgcn_exp2f) && __has_builtin(__builtin_amdgcn_rcpf)
  float e = __builtin_amdgcn_exp2f(x * 2.8853900817779268f);   // e^{2x}
  return __builtin_fmaf(-2.0f, __builtin_amdgcn_rcpf(e + 1.0f), 1.0f);
#else
  float e = __expf(2.0f * x);
  return 1.0f - 2.0f / (e + 1.0f);
#endif
}

__global__ __launch_bounds__(512, 1) void sde_kernel(
    const float* __restrict__ z0, const int* __restrict__ idx,
    const float* __restrict__ W1, const float* __restrict__ b1,
    const float* __restrict__ W2, const float* __restrict__ b2,
    const float* __restrict__ log_noise, const float* __restrict__ noise,
    float* __restrict__ out)
{
  const int tid   = threadIdx.x;
  const int lane  = tid & 63;
  const int v     = tid >> 6;              // wave in block 0..7
  const int q     = lane & 3;
  const int pslot = (lane >> 4) & 1;
  const int B     = blockIdx.x;
  const int kk    = (v < 4) ? (B * 4 + v) : (2047 - (B * 4 + (v - 4)));
  const int P     = 2 * kk + pslot;        // this lane's particle
  const int pmax  = 2 * kk + 1;            // steps the wave runs
  const int lam32 = (lane & 15) | ((lane >> 1) & 16);
  const int j0 = lam32, j1 = lam32 + 32;   // this lane's 2 hidden units

  // weights in registers, local dim order d = 2q ^ i
  float w1a[8], w1b[8], w2a[8], w2b[8];
#pragma unroll
  for (int i = 0; i < 8; ++i) {
    const int d = (2 * q) ^ i;
    w1a[i] = W1[d * 64 + j0];
    w1b[i] = W1[d * 64 + j1];
    w2a[i] = W2[j0 * 8 + d];
    w2b[i] = W2[j1 * 8 + d];
  }
  const float bb1a = b1[j0], bb1b = b1[j1];
  const float dt   = 1.0f / 4095.0f;
  const float csig = __expf(log_noise[0]) * sqrtf(dt);
  const float bdt0 = b2[2 * q] * dt;
  const float bdt1 = b2[2 * q + 1] * dt;

  const float2 yz = ((const float2*)z0)[(size_t)idx[P] * 4 + q];
  float y0 = yz.x, y1 = yz.y;      // own dims 2q, 2q+1
  float s0 = y0, s1 = y1;          // snapshot (record of particle 2kk)

  // noise: uniform base pointer + per-lane const offset -> saddr+voffset loads
  const float2* __restrict__ nbase = (const float2*)noise;
  const int loff = P * 4 + q;
  // prefetch 8 rows (rows 0..7 always exist: 4095 rows total)
  float2 e0 = nbase[loff + (size_t)0 * ROW2];
  float2 e1 = nbase[loff + (size_t)1 * ROW2];
  float2 e2 = nbase[loff + (size_t)2 * ROW2];
  float2 e3 = nbase[loff + (size_t)3 * ROW2];
  float2 e4 = nbase[loff + (size_t)4 * ROW2];
  float2 e5 = nbase[loff + (size_t)5 * ROW2];
  float2 e6 = nbase[loff + (size_t)6 * ROW2];
  float2 e7 = nbase[loff + (size_t)7 * ROW2];
  nbase += (size_t)8 * ROW2;
  int nld = 8;

  auto step = [&](float2 ee) {
    // gather: local dims 2,3 from q^1, 4,5 from q^2, 6,7 from q^3 (quad DPP)
    const float g2 = fdpp<0xB1>(y0), g3 = fdpp<0xB1>(y1);
    const float g4 = fdpp<0x4E>(y0), g5 = fdpp<0x4E>(y1);
    const float g6 = fdpp<0x1B>(y0), g7 = fdpp<0x1B>(y1);
    // layer 1: two 4-FMA chains per unit, then join
    float pa = __builtin_fmaf(y0, w1a[0], bb1a);
    pa = __builtin_fmaf(y1, w1a[1], pa);
    pa = __builtin_fmaf(g2, w1a[2], pa);
    pa = __builtin_fmaf(g3, w1a[3], pa);
    float pa2 = g4 * w1a[4];
    pa2 = __builtin_fmaf(g5, w1a[5], pa2);
    pa2 = __builtin_fmaf(g6, w1a[6], pa2);
    pa2 = __builtin_fmaf(g7, w1a[7], pa2);
    pa += pa2;
    float pb = __builtin_fmaf(y0, w1b[0], bb1b);
    pb = __builtin_fmaf(y1, w1b[1], pb);
    pb = __builtin_fmaf(g2, w1b[2], pb);
    pb = __builtin_fmaf(g3, w1b[3], pb);
    float pb2 = g4 * w1b[4];
    pb2 = __builtin_fmaf(g5, w1b[5], pb2);
    pb2 = __builtin_fmaf(g6, w1b[6], pb2);
    pb2 = __builtin_fmaf(g7, w1b[7], pb2);
    pb += pb2;
    const float ha = fast_tanh(pa);
    const float hb = fast_tanh(pb);
    // layer 2 partials in local dim order
    float acc[8];
#pragma unroll
    for (int i = 0; i < 8; ++i)
      acc[i] = __builtin_fmaf(hb, w2b[i], ha * w2a[i]);
    // quad fold, select-free: stage xor2 then xor1
    const float f0 = acc[0] + fdpp<0x4E>(acc[4]);
    const float f1 = acc[1] + fdpp<0x4E>(acc[5]);
    const float f2 = acc[2] + fdpp<0x4E>(acc[6]);
    const float f3 = acc[3] + fdpp<0x4E>(acc[7]);
    float r0 = f0 + fdpp<0xB1>(f2);
    float r1 = f1 + fdpp<0xB1>(f3);
    // replica sum over lane bits 2,3,5 (all VALU)
    r0 += get_x4(r0);  r1 += get_x4(r1);
    r0 += get_x8(r0);  r1 += get_x8(r1);
    r0 = sum_x32(r0);  r1 = sum_x32(r1);
    // update: y += csig*eps + dt*drift + b2*dt
    y0 = __builtin_fmaf(csig, ee.x, y0);
    y0 = __builtin_fmaf(dt, r0, y0);
    y0 += bdt0;
    y1 = __builtin_fmaf(csig, ee.y, y1);
    y1 = __builtin_fmaf(dt, r1, y1);
    y1 += bdt1;
  };

#define SUBSTEP(EK, SS, SNAP)                                  \
  step(EK);                                                    \
  if (SNAP) { if ((SS) == pmax - 1) { s0 = y0; s1 = y1; } }    \
  if (nld <= LASTROW) { EK = nbase[loff]; }                    \
  nbase += ROW2; ++nld;

  for (int s = 1; s <= pmax; s += 8) {
    SUBSTEP(e0, s, false)
    if (s + 1 > pmax) break;
    SUBSTEP(e1, s + 1, true)
    if (s + 2 > pmax) break;
    SUBSTEP(e2, s + 2, false)
    if (s + 3 > pmax) break;
    SUBSTEP(e3, s + 3, true)
    if (s + 4 > pmax) break;
    SUBSTEP(e4, s + 4, false)
    if (s + 5 > pmax) break;
    SUBSTEP(e5, s + 5, true)
    if (s + 6 > pmax) break;
    SUBSTEP(e6, s + 6, false)
    if (s + 7 > pmax) break;
    SUBSTEP(e7, s + 7, true)
  }
#undef SUBSTEP

  // store: one replica (lane bits 2,3,5 == 0): pslot 0 -> snapshot, 1 -> final
  if ((lane & 0x2C) == 0) {
    float2 o;
    o.x = pslot ? y0 : s0;
    o.y = pslot ? y1 : s1;
    ((float2*)out)[(size_t)P * 4 + q] = o;
  }
}

extern "C" void kernel_launch(void* const* d_in, const int* in_sizes, int n_in,
                              void* d_out, int out_size, void* d_ws, size_t ws_size,
                              hipStream_t stream) {
  const float* z0    = (const float*)d_in[0];
  const int*   idx   = (const int*)d_in[1];
  const float* W1    = (const float*)d_in[2];
  const float* b1    = (const float*)d_in[3];
  const float* W2    = (const float*)d_in[4];
  const float* b2    = (const float*)d_in[5];
  const float* ln    = (const float*)d_in[6];
  const float* noise = (const float*)d_in[7];
  float* out = (float*)d_out;
  (void)d_ws; (void)ws_size; (void)in_sizes; (void)n_in; (void)out_size;
  // 256 blocks x 512 threads = 2048 waves; complementary pairing per SIMD
  hipLaunchKernelGGL(sde_kernel, dim3(256), dim3(512), 0, stream,
                     z0, idx, W1, b1, W2, b2, ln, noise, out);
}

// Round 4
// 929.191 us; speedup vs baseline: 1.9291x; 1.0581x over previous
//
#include <hip/hip_runtime.h>
#include <math.h>

// SDE Euler-Maruyama, triangular schedule, ALL cross-lane ops VALU-only.
//
// Layout per wave (64 lanes): 2 particles. Lane bits:
//   bits 0,1 = q      : dim-slot, lane owns dims {2q, 2q+1} of y
//   bits 2,3,5        : replica index (8 replicas of the quad)
//   bit 4   = pslot   : which of the wave's 2 particles
// 32 lanes per particle hold 64 hidden units (2 per lane, j0=lam32, j1=lam32+32).
//
// Cross-lane moves (all VALU, no DS): quad_perm xor1/2/3 (DPP),
// row_half_mirror (xor7), row_mirror (xor15), v_permlane32_swap_b32 (xor32).
// xor4 = RHM∘quad3, xor8 = RM∘RHM. Local dim order d = 2q ^ i makes the quad
// fold select-free.
//
// Round-4 changes:
//  * Loads are UNCONDITIONAL (pointer clamped by uniform scalar select) so the
//    waitcnt pass can count vmcnt per prefetch register instead of draining
//    vmcnt(0) every substep (round-3: ~640 cyc/step, ~430 of them stall).
//  * dt folded into w2; b2*dt injected once via replica-0 acc init; noise fma
//    computed in parallel with the reduce -> post-reduce chain is 1 add.
//  * Both permlane32_swaps share one asm block (shared hazard nops).
//
// SIMD balancing: block B wave v<4 -> pair k=4B+v (short chain), wave v+4 ->
// k=2047-4B-v (long chain). Waves v and v+4 share a SIMD (v%4 round-robin),
// so every SIMD totals exactly 4096 wave-steps.

#define ROW2 16384          // float2 elements per noise row (4096*8/2)
#define LASTROW 4094        // valid noise rows 0..4094

template<int CTRL>
__device__ __forceinline__ float fdpp(float x) {
  return __builtin_bit_cast(float, __builtin_amdgcn_update_dpp(
      0, __builtin_bit_cast(int, x), CTRL, 0xF, 0xF, true));
}

// value from lane^4:  RHM gives x[l^7], quad xor3 of that gives x[l^4]
__device__ __forceinline__ float get_x4(float x) {
  return fdpp<0x1B>(fdpp<0x141>(x));
}
// value from lane^8:  RM gives x[l^15], RHM of that gives x[l^8]
__device__ __forceinline__ float get_x8(float x) {
  return fdpp<0x141>(fdpp<0x140>(x));
}
// (r0 += r0[lane^32]; r1 += r1[lane^32]) via v_permlane32_swap, one asm block.
// s_nop 1 on both sides = manual wait states (inline asm gets no compiler
// hazard mitigation; VALU-write->permlane-read and permlane-write->VALU-read).
__device__ __forceinline__ void sum_x32_2(float& r0, float& r1) {
  float a0 = r0, b0 = r0, a1 = r1, b1 = r1;
  asm("s_nop 1\n\t"
      "v_permlane32_swap_b32 %0, %1\n\t"
      "v_permlane32_swap_b32 %2, %3\n\t"
      "s_nop 1"
      : "+v"(a0), "+v"(b0), "+v"(a1), "+v"(b1));
  r0 = a0 + b0;
  r1 = a1 + b1;
}

__device__ __forceinline__ float fast_tanh(float x) {
#if __has_builtin(__builtin_amdgcn_exp2f) && __has_builtin(__builtin_amdgcn_rcpf)
  float e = __builtin_amdgcn_exp2f(x * 2.8853900817779268f);   // e^{2x}
  return __builtin_fmaf(-2.0f, __builtin_amdgcn_rcpf(e + 1.0f), 1.0f);
#else
  float e = __expf(2.0f * x);
  return 1.0f - 2.0f / (e + 1.0f);
#endif
}

__global__ __launch_bounds__(512, 1) void sde_kernel(
    const float* __restrict__ z0, const int* __restrict__ idx,
    const float* __restrict__ W1, const float* __restrict__ b1,
    const float* __restrict__ W2, const float* __restrict__ b2,
    const float* __restrict__ log_noise, const float* __restrict__ noise,
    float* __restrict__ out)
{
  const int tid   = threadIdx.x;
  const int lane  = tid & 63;
  const int v     = tid >> 6;              // wave in block 0..7
  const int q     = lane & 3;
  const int pslot = (lane >> 4) & 1;
  const int B     = blockIdx.x;
  const int kk    = (v < 4) ? (B * 4 + v) : (2047 - (B * 4 + (v - 4)));
  const int P     = 2 * kk + pslot;        // this lane's particle
  const int pmax  = 2 * kk + 1;            // steps the wave runs
  const int lam32 = (lane & 15) | ((lane >> 1) & 16);
  const int j0 = lam32, j1 = lam32 + 32;   // this lane's 2 hidden units
  const bool rep0 = (lane & 0x2C) == 0;    // replica bits 2,3,5 all zero

  const float dt = 1.0f / 4095.0f;

  // weights in registers, local dim order d = 2q ^ i; dt folded into w2
  float w1a[8], w1b[8], w2a[8], w2b[8];
#pragma unroll
  for (int i = 0; i < 8; ++i) {
    const int d = (2 * q) ^ i;
    w1a[i] = W1[d * 64 + j0];
    w1b[i] = W1[d * 64 + j1];
    w2a[i] = W2[j0 * 8 + d] * dt;
    w2b[i] = W2[j1 * 8 + d] * dt;
  }
  const float bb1a = b1[j0], bb1b = b1[j1];
  // b2*dt injected once per dim via replica-0 lanes' acc[0]/acc[1] init
  const float c0 = rep0 ? b2[2 * q] * dt : 0.0f;
  const float c1 = rep0 ? b2[2 * q + 1] * dt : 0.0f;
  const float csig = __expf(log_noise[0]) * sqrtf(dt);

  const float2 yz = ((const float2*)z0)[(size_t)idx[P] * 4 + q];
  float y0 = yz.x, y1 = yz.y;      // own dims 2q, 2q+1
  float s0 = y0, s1 = y1;          // snapshot (record of particle 2kk)

  // noise: uniform base pointer + per-lane const offset -> saddr+voffset loads
  const float2* __restrict__ nbase = (const float2*)noise;
  const int loff = P * 4 + q;
  // prefetch 8 rows (rows 0..7 always exist: 4095 rows total)
  float2 e0 = nbase[loff + (size_t)0 * ROW2];
  float2 e1 = nbase[loff + (size_t)1 * ROW2];
  float2 e2 = nbase[loff + (size_t)2 * ROW2];
  float2 e3 = nbase[loff + (size_t)3 * ROW2];
  float2 e4 = nbase[loff + (size_t)4 * ROW2];
  float2 e5 = nbase[loff + (size_t)5 * ROW2];
  float2 e6 = nbase[loff + (size_t)6 * ROW2];
  float2 e7 = nbase[loff + (size_t)7 * ROW2];
  nbase += (size_t)8 * ROW2;
  int nld = 8;

  auto step = [&](float2 ee) {
    // noise term, independent of the MLP/reduce -> off the critical path
    const float z0n = __builtin_fmaf(csig, ee.x, y0);
    const float z1n = __builtin_fmaf(csig, ee.y, y1);
    // gather: local dims 2,3 from q^1, 4,5 from q^2, 6,7 from q^3 (quad DPP)
    const float g2 = fdpp<0xB1>(y0), g3 = fdpp<0xB1>(y1);
    const float g4 = fdpp<0x4E>(y0), g5 = fdpp<0x4E>(y1);
    const float g6 = fdpp<0x1B>(y0), g7 = fdpp<0x1B>(y1);
    // layer 1: two 4-FMA chains per unit, then join
    float pa = __builtin_fmaf(y0, w1a[0], bb1a);
    pa = __builtin_fmaf(y1, w1a[1], pa);
    pa = __builtin_fmaf(g2, w1a[2], pa);
    pa = __builtin_fmaf(g3, w1a[3], pa);
    float pa2 = g4 * w1a[4];
    pa2 = __builtin_fmaf(g5, w1a[5], pa2);
    pa2 = __builtin_fmaf(g6, w1a[6], pa2);
    pa2 = __builtin_fmaf(g7, w1a[7], pa2);
    pa += pa2;
    float pb = __builtin_fmaf(y0, w1b[0], bb1b);
    pb = __builtin_fmaf(y1, w1b[1], pb);
    pb = __builtin_fmaf(g2, w1b[2], pb);
    pb = __builtin_fmaf(g3, w1b[3], pb);
    float pb2 = g4 * w1b[4];
    pb2 = __builtin_fmaf(g5, w1b[5], pb2);
    pb2 = __builtin_fmaf(g6, w1b[6], pb2);
    pb2 = __builtin_fmaf(g7, w1b[7], pb2);
    pb += pb2;
    const float ha = fast_tanh(pa);
    const float hb = fast_tanh(pb);
    // layer 2 partials in local dim order (w2 pre-scaled by dt; bias in c0/c1)
    float acc[8];
    acc[0] = __builtin_fmaf(hb, w2b[0], __builtin_fmaf(ha, w2a[0], c0));
    acc[1] = __builtin_fmaf(hb, w2b[1], __builtin_fmaf(ha, w2a[1], c1));
#pragma unroll
    for (int i = 2; i < 8; ++i)
      acc[i] = __builtin_fmaf(hb, w2b[i], ha * w2a[i]);
    // quad fold, select-free: stage xor2 then xor1
    const float f0 = acc[0] + fdpp<0x4E>(acc[4]);
    const float f1 = acc[1] + fdpp<0x4E>(acc[5]);
    const float f2 = acc[2] + fdpp<0x4E>(acc[6]);
    const float f3 = acc[3] + fdpp<0x4E>(acc[7]);
    float r0 = f0 + fdpp<0xB1>(f2);
    float r1 = f1 + fdpp<0xB1>(f3);
    // replica sum over lane bits 2,3,5 (all VALU)
    r0 += get_x4(r0);  r1 += get_x4(r1);
    r0 += get_x8(r0);  r1 += get_x8(r1);
    sum_x32_2(r0, r1);
    // update: r already contains dt*drift + b2*dt
    y0 = z0n + r0;
    y1 = z1n + r1;
  };

  // Loads are unconditional; the row pointer stops advancing at LASTROW
  // (uniform scalar select). Over-end loads re-read row LASTROW and are
  // never consumed (the loop breaks first).
#define SUBSTEP(EK, SS, SNAP)                                  \
  step(EK);                                                    \
  if (SNAP) { if ((SS) == pmax - 1) { s0 = y0; s1 = y1; } }    \
  EK = nbase[loff];                                            \
  nbase += (nld < LASTROW) ? ROW2 : 0;                         \
  ++nld;

  for (int s = 1; s <= pmax; s += 8) {
    SUBSTEP(e0, s, false)
    if (s + 1 > pmax) break;
    SUBSTEP(e1, s + 1, true)
    if (s + 2 > pmax) break;
    SUBSTEP(e2, s + 2, false)
    if (s + 3 > pmax) break;
    SUBSTEP(e3, s + 3, true)
    if (s + 4 > pmax) break;
    SUBSTEP(e4, s + 4, false)
    if (s + 5 > pmax) break;
    SUBSTEP(e5, s + 5, true)
    if (s + 6 > pmax) break;
    SUBSTEP(e6, s + 6, false)
    if (s + 7 > pmax) break;
    SUBSTEP(e7, s + 7, true)
  }
#undef SUBSTEP

  // store: one replica (lane bits 2,3,5 == 0): pslot 0 -> snapshot, 1 -> final
  if (rep0) {
    float2 o;
    o.x = pslot ? y0 : s0;
    o.y = pslot ? y1 : s1;
    ((float2*)out)[(size_t)P * 4 + q] = o;
  }
}

extern "C" void kernel_launch(void* const* d_in, const int* in_sizes, int n_in,
                              void* d_out, int out_size, void* d_ws, size_t ws_size,
                              hipStream_t stream) {
  const float* z0    = (const float*)d_in[0];
  const int*   idx   = (const int*)d_in[1];
  const float* W1    = (const float*)d_in[2];
  const float* b1    = (const float*)d_in[3];
  const float* W2    = (const float*)d_in[4];
  const float* b2    = (const float*)d_in[5];
  const float* ln    = (const float*)d_in[6];
  const float* noise = (const float*)d_in[7];
  float* out = (float*)d_out;
  (void)d_ws; (void)ws_size; (void)in_sizes; (void)n_in; (void)out_size;
  // 256 blocks x 512 threads = 2048 waves; complementary pairing per SIMD
  hipLaunchKernelGGL(sde_kernel, dim3(256), dim3(512), 0, stream,
                     z0, idx, W1, b1, W2, b2, ln, noise, out);
}

// Round 5
// 789.659 us; speedup vs baseline: 2.2700x; 1.1767x over previous
//
#include <hip/hip_runtime.h>
#include <math.h>

// SDE Euler-Maruyama, triangular schedule, ALL cross-lane ops VALU-only.
//
// Layout per wave (64 lanes): 2 particles. Lane bits:
//   bits 0,1 = q      : dim-slot, lane owns dims {2q, 2q+1} of y
//   bits 2,3,5        : replica index (8 replicas of the quad)
//   bit 4   = pslot   : which of the wave's 2 particles
// 32 lanes per particle hold 64 hidden units (2 per lane, j0=lam32, j1=lam32+32).
//
// Cross-lane moves (all VALU, no DS): quad_perm xor1/2/3 (DPP),
// row_half_mirror (xor7), row_mirror (xor15), v_permlane32_swap_b32 (xor32).
// xor4 = RHM∘quad3, xor8 = RM∘RHM. Local dim order d = 2q ^ i makes the quad
// fold select-free.
//
// Round-5 change: ZERO control flow inside the unrolled body. Previously each
// of the 8 substeps was followed by `if (s+k > pmax) break` — 8 CF joins per
// iteration forced conservative s_waitcnt drains and blocked cross-substep
// scheduling (round-4: 625 cyc/step solo vs ~180 model). Now:
//  * capture-by-compare: particle P's record is y after exactly P steps and
//    P = 2kk+pslot is per-lane, so `if (ss == P) snapshot` (v_cmp + cndmask)
//    replaces both the snapshot branch and precise loop exit;
//  * every wave runs ceil(pmax/8)*8 steps; extra steps integrate clamped
//    noise rows and are discarded (tanh-bounded, no overflow in <=7 steps);
//  * loads stay unconditional with scalar-clamped pointer advance.
//
// SIMD balancing: block B wave v<4 -> pair k=4B+v (short chain), wave v+4 ->
// k=2047-4B-v (long chain). Waves v and v+4 share a SIMD (v%4 round-robin),
// so every SIMD totals ~4096 wave-steps.

#define ROW2 16384          // float2 elements per noise row (4096*8/2)
#define LASTROW 4094        // valid noise rows 0..4094

template<int CTRL>
__device__ __forceinline__ float fdpp(float x) {
  return __builtin_bit_cast(float, __builtin_amdgcn_update_dpp(
      0, __builtin_bit_cast(int, x), CTRL, 0xF, 0xF, true));
}

// value from lane^4:  RHM gives x[l^7], quad xor3 of that gives x[l^4]
__device__ __forceinline__ float get_x4(float x) {
  return fdpp<0x1B>(fdpp<0x141>(x));
}
// value from lane^8:  RM gives x[l^15], RHM of that gives x[l^8]
__device__ __forceinline__ float get_x8(float x) {
  return fdpp<0x141>(fdpp<0x140>(x));
}
// (r0 += r0[lane^32]; r1 += r1[lane^32]) via v_permlane32_swap, one asm block.
// s_nop 1 on both sides = manual wait states (inline asm gets no compiler
// hazard mitigation; VALU-write->permlane-read and permlane-write->VALU-read).
__device__ __forceinline__ void sum_x32_2(float& r0, float& r1) {
  float a0 = r0, b0 = r0, a1 = r1, b1 = r1;
  asm("s_nop 1\n\t"
      "v_permlane32_swap_b32 %0, %1\n\t"
      "v_permlane32_swap_b32 %2, %3\n\t"
      "s_nop 1"
      : "+v"(a0), "+v"(b0), "+v"(a1), "+v"(b1));
  r0 = a0 + b0;
  r1 = a1 + b1;
}

__device__ __forceinline__ float fast_tanh(float x) {
#if __has_builtin(__builtin_amdgcn_exp2f) && __has_builtin(__builtin_amdgcn_rcpf)
  float e = __builtin_amdgcn_exp2f(x * 2.8853900817779268f);   // e^{2x}
  return __builtin_fmaf(-2.0f, __builtin_amdgcn_rcpf(e + 1.0f), 1.0f);
#else
  float e = __expf(2.0f * x);
  return 1.0f - 2.0f / (e + 1.0f);
#endif
}

__global__ __launch_bounds__(512, 1) void sde_kernel(
    const float* __restrict__ z0, const int* __restrict__ idx,
    const float* __restrict__ W1, const float* __restrict__ b1,
    const float* __restrict__ W2, const float* __restrict__ b2,
    const float* __restrict__ log_noise, const float* __restrict__ noise,
    float* __restrict__ out)
{
  const int tid   = threadIdx.x;
  const int lane  = tid & 63;
  const int v     = tid >> 6;              // wave in block 0..7
  const int q     = lane & 3;
  const int pslot = (lane >> 4) & 1;
  const int B     = blockIdx.x;
  const int kk    = (v < 4) ? (B * 4 + v) : (2047 - (B * 4 + (v - 4)));
  const int P     = 2 * kk + pslot;        // this lane's particle
  const int pmax  = 2 * kk + 1;            // steps the wave must cover
  const int lam32 = (lane & 15) | ((lane >> 1) & 16);
  const int j0 = lam32, j1 = lam32 + 32;   // this lane's 2 hidden units
  const bool rep0 = (lane & 0x2C) == 0;    // replica bits 2,3,5 all zero

  const float dt = 1.0f / 4095.0f;

  // weights in registers, local dim order d = 2q ^ i; dt folded into w2
  float w1a[8], w1b[8], w2a[8], w2b[8];
#pragma unroll
  for (int i = 0; i < 8; ++i) {
    const int d = (2 * q) ^ i;
    w1a[i] = W1[d * 64 + j0];
    w1b[i] = W1[d * 64 + j1];
    w2a[i] = W2[j0 * 8 + d] * dt;
    w2b[i] = W2[j1 * 8 + d] * dt;
  }
  const float bb1a = b1[j0], bb1b = b1[j1];
  // b2*dt injected once per dim via replica-0 lanes' acc[0]/acc[1] init
  const float c0 = rep0 ? b2[2 * q] * dt : 0.0f;
  const float c1 = rep0 ? b2[2 * q + 1] * dt : 0.0f;
  const float csig = __expf(log_noise[0]) * sqrtf(dt);

  const float2 yz = ((const float2*)z0)[(size_t)idx[P] * 4 + q];
  float y0 = yz.x, y1 = yz.y;      // own dims 2q, 2q+1
  float s0 = y0, s1 = y1;          // captured record (P==0: initial state)

  // noise: uniform base pointer + per-lane const offset -> saddr+voffset loads
  const float2* __restrict__ nbase = (const float2*)noise;
  const int loff = P * 4 + q;
  // prefetch 8 rows (rows 0..7 always exist: 4095 rows total)
  float2 e0 = nbase[loff + (size_t)0 * ROW2];
  float2 e1 = nbase[loff + (size_t)1 * ROW2];
  float2 e2 = nbase[loff + (size_t)2 * ROW2];
  float2 e3 = nbase[loff + (size_t)3 * ROW2];
  float2 e4 = nbase[loff + (size_t)4 * ROW2];
  float2 e5 = nbase[loff + (size_t)5 * ROW2];
  float2 e6 = nbase[loff + (size_t)6 * ROW2];
  float2 e7 = nbase[loff + (size_t)7 * ROW2];
  nbase += (size_t)8 * ROW2;
  int nld = 8;

  auto step = [&](float2 ee) {
    // noise term, independent of the MLP/reduce -> off the critical path
    const float z0n = __builtin_fmaf(csig, ee.x, y0);
    const float z1n = __builtin_fmaf(csig, ee.y, y1);
    // gather: local dims 2,3 from q^1, 4,5 from q^2, 6,7 from q^3 (quad DPP)
    const float g2 = fdpp<0xB1>(y0), g3 = fdpp<0xB1>(y1);
    const float g4 = fdpp<0x4E>(y0), g5 = fdpp<0x4E>(y1);
    const float g6 = fdpp<0x1B>(y0), g7 = fdpp<0x1B>(y1);
    // layer 1: two 4-FMA chains per unit, then join
    float pa = __builtin_fmaf(y0, w1a[0], bb1a);
    pa = __builtin_fmaf(y1, w1a[1], pa);
    pa = __builtin_fmaf(g2, w1a[2], pa);
    pa = __builtin_fmaf(g3, w1a[3], pa);
    float pa2 = g4 * w1a[4];
    pa2 = __builtin_fmaf(g5, w1a[5], pa2);
    pa2 = __builtin_fmaf(g6, w1a[6], pa2);
    pa2 = __builtin_fmaf(g7, w1a[7], pa2);
    pa += pa2;
    float pb = __builtin_fmaf(y0, w1b[0], bb1b);
    pb = __builtin_fmaf(y1, w1b[1], pb);
    pb = __builtin_fmaf(g2, w1b[2], pb);
    pb = __builtin_fmaf(g3, w1b[3], pb);
    float pb2 = g4 * w1b[4];
    pb2 = __builtin_fmaf(g5, w1b[5], pb2);
    pb2 = __builtin_fmaf(g6, w1b[6], pb2);
    pb2 = __builtin_fmaf(g7, w1b[7], pb2);
    pb += pb2;
    const float ha = fast_tanh(pa);
    const float hb = fast_tanh(pb);
    // layer 2 partials in local dim order (w2 pre-scaled by dt; bias in c0/c1)
    float acc[8];
    acc[0] = __builtin_fmaf(hb, w2b[0], __builtin_fmaf(ha, w2a[0], c0));
    acc[1] = __builtin_fmaf(hb, w2b[1], __builtin_fmaf(ha, w2a[1], c1));
#pragma unroll
    for (int i = 2; i < 8; ++i)
      acc[i] = __builtin_fmaf(hb, w2b[i], ha * w2a[i]);
    // quad fold, select-free: stage xor2 then xor1
    const float f0 = acc[0] + fdpp<0x4E>(acc[4]);
    const float f1 = acc[1] + fdpp<0x4E>(acc[5]);
    const float f2 = acc[2] + fdpp<0x4E>(acc[6]);
    const float f3 = acc[3] + fdpp<0x4E>(acc[7]);
    float r0 = f0 + fdpp<0xB1>(f2);
    float r1 = f1 + fdpp<0xB1>(f3);
    // replica sum over lane bits 2,3,5 (all VALU)
    r0 += get_x4(r0);  r1 += get_x4(r1);
    r0 += get_x8(r0);  r1 += get_x8(r1);
    sum_x32_2(r0, r1);
    // update: r already contains dt*drift + b2*dt
    y0 = z0n + r0;
    y1 = z1n + r1;
  };

  // Branch-free substep: step; capture-by-compare (ss==P); unconditional
  // reload; scalar-clamped pointer advance.
  int ss = 1;
#define SUBSTEP(EK)                                            \
  step(EK);                                                    \
  {                                                            \
    const bool cap = (ss == P);                                \
    s0 = cap ? y0 : s0;                                        \
    s1 = cap ? y1 : s1;                                        \
  }                                                            \
  EK = nbase[loff];                                            \
  nbase += (nld < LASTROW) ? ROW2 : 0;                         \
  ++nld; ++ss;

  const int T8 = (pmax + 7) >> 3;   // ceil(pmax/8) iterations, no inner CF
  for (int it = 0; it < T8; ++it) {
    SUBSTEP(e0)
    SUBSTEP(e1)
    SUBSTEP(e2)
    SUBSTEP(e3)
    SUBSTEP(e4)
    SUBSTEP(e5)
    SUBSTEP(e6)
    SUBSTEP(e7)
  }
#undef SUBSTEP

  // store: one replica (lane bits 2,3,5 == 0); both pslots store the capture
  if (rep0) {
    float2 o;
    o.x = s0;
    o.y = s1;
    ((float2*)out)[(size_t)P * 4 + q] = o;
  }
}

extern "C" void kernel_launch(void* const* d_in, const int* in_sizes, int n_in,
                              void* d_out, int out_size, void* d_ws, size_t ws_size,
                              hipStream_t stream) {
  const float* z0    = (const float*)d_in[0];
  const int*   idx   = (const int*)d_in[1];
  const float* W1    = (const float*)d_in[2];
  const float* b1    = (const float*)d_in[3];
  const float* W2    = (const float*)d_in[4];
  const float* b2    = (const float*)d_in[5];
  const float* ln    = (const float*)d_in[6];
  const float* noise = (const float*)d_in[7];
  float* out = (float*)d_out;
  (void)d_ws; (void)ws_size; (void)in_sizes; (void)n_in; (void)out_size;
  // 256 blocks x 512 threads = 2048 waves; complementary pairing per SIMD
  hipLaunchKernelGGL(sde_kernel, dim3(256), dim3(512), 0, stream,
                     z0, idx, W1, b1, W2, b2, ln, noise, out);
}